// Round 7
// baseline (384.302 us; speedup 1.0000x reference)
//
#include <hip/hip_runtime.h>
#include <hip/hip_bf16.h>

// LSTMAggregator — ROUND 7: kill the register spills.
// R6 counters: WRITE_SIZE 238 MB vs 25.6 MB of actual output => ~30 VGPRs
// spilled per thread, rewritten every K-step (~230 MB scratch writebacks).
// Budget was blown by weights(96) + acc(64) + x-prefetch(32) + state(32).
// R7: drop x-LDS staging + prefetch entirely; x A-frags load straight from
// global (rows are shared by all 4 waves -> L1/L2 hot). Register total ~230
// < 256 cap at launch_bounds(256,2) -> no spill, 2 blocks/CU.
//
// Block = 256 threads = 64 nodes. Wave w owns all 4 gates of hidden units
// w*16..w*16+15 for all 64 nodes; weight B-frags stay in registers for the
// whole kernel. h exchanged cross-wave via padded LDS.
//   A-frag: A[m=lane&15][k=(lane>>4)*8+j]   B-frag: B[k][n=lane&15]=W[row][k]
//   C/D: row(node-in-group)=(lane>>4)*4+reg, col=lane&15 -> unit w*16+(lane&15)

#define NN 50000
#define KK 10
#define FF 128
#define HH 64

// ws layout (bf16 elements)
#define WS_WIH_F 0
#define WS_WHH_F 32768
#define WS_WIH_B 49152

#define HS 72    // h_lds row stride (shorts): 64+8 pad -> 2-way-max conflicts

typedef __bf16 bf16x8 __attribute__((ext_vector_type(8)));
typedef float f32x4 __attribute__((ext_vector_type(4)));

__device__ __forceinline__ float fast_sig(float x) {
    float e = exp2f(x * -1.44269504f);
    return __builtin_amdgcn_rcpf(1.0f + e);
}
__device__ __forceinline__ float fast_tanh(float x) {
    float xx = fminf(fmaxf(x, -15.0f), 15.0f);
    float e = exp2f(xx * 2.88539008f);
    return (e - 1.0f) * __builtin_amdgcn_rcpf(e + 1.0f);
}

__device__ __forceinline__ bf16x8 load_cvt8(const float* p) {
    f32x4 lo = *(const f32x4*)p;
    f32x4 hi = *(const f32x4*)(p + 4);
    bf16x8 r;
#pragma unroll
    for (int j = 0; j < 4; ++j) { r[j] = (__bf16)lo[j]; r[4 + j] = (__bf16)hi[j]; }
    return r;
}

__global__ void cvt_weights_kernel(const float* __restrict__ Wih_f,
                                   const float* __restrict__ Whh_f,
                                   const float* __restrict__ Wih_b,
                                   __bf16* __restrict__ ws) {
    int i = blockIdx.x * 256 + threadIdx.x;          // 32768 threads
    ws[WS_WIH_F + i] = (__bf16)Wih_f[i];
    if (i < 16384) ws[WS_WHH_F + i] = (__bf16)Whh_f[i];
    ws[WS_WIH_B + i] = (__bf16)Wih_b[i];
}

__global__ __launch_bounds__(256, 2) void lstm_agg_kernel(
    const int* __restrict__ nidx,
    const float* __restrict__ tab,
    const float* __restrict__ bih_f,
    const float* __restrict__ bhh_f,
    const float* __restrict__ bih_b,
    const float* __restrict__ bhh_b,
    const __bf16* __restrict__ ws,
    float* __restrict__ out)
{
    __shared__ __bf16 h_lds[64 * HS];   // 9216 B
    __shared__ int    gq[64][KK];       // 2560 B

    const int tid  = threadIdx.x;
    const int w    = tid >> 6;        // wave id: owns units w*16..w*16+15
    const int lane = tid & 63;
    const int q    = lane >> 4;
    const int c    = lane & 15;
    const int koff = q * 8;           // f-offset of this quad within a 32-chunk
    const int node_base = blockIdx.x * 64;

    // stage gather indices for the block's 64 nodes
    for (int i = tid; i < 64 * KK; i += 256) {
        int r = i / KK, k = i - r * KK;
        int node = min(node_base + r, NN - 1);
        gq[r][k] = nidx[node * KK + k];
    }

    // forward weights: register-resident B-fragments for the whole kernel
    bf16x8 bWih[4][4], bWhh[4][2];
#pragma unroll
    for (int g = 0; g < 4; ++g) {
        int row = (g * 4 + w) * 16 + c;        // gate row g*64 + w*16 + c
#pragma unroll
        for (int kk = 0; kk < 4; ++kk)
            bWih[g][kk] = *(const bf16x8*)(ws + WS_WIH_F + row * FF + kk * 32 + koff);
#pragma unroll
        for (int kk = 0; kk < 2; ++kk)
            bWhh[g][kk] = *(const bf16x8*)(ws + WS_WHH_F + row * HH + kk * 32 + koff);
    }

    float bias[4];
#pragma unroll
    for (int g = 0; g < 4; ++g) {
        int u = g * 64 + w * 16 + c;
        bias[g] = bih_f[u] + bhh_f[u];
    }

    __syncthreads();   // gq visible

    f32x4 acc[4][4];      // [gate][node-group]
    float cst[4][4];      // [group][reg] cell state
#pragma unroll
    for (int r = 0; r < 4; ++r)
#pragma unroll
        for (int reg = 0; reg < 4; ++reg) cst[r][reg] = 0.0f;

    for (int k = 0; k < KK; ++k) {
#pragma unroll
        for (int g = 0; g < 4; ++g)
#pragma unroll
            for (int r = 0; r < 4; ++r)
                acc[g][r] = (f32x4){bias[g], bias[g], bias[g], bias[g]};

        // x_k @ Wih^T : A-frags straight from global (rows L1/L2-hot across waves)
#pragma unroll
        for (int r = 0; r < 4; ++r) {
            const float* xrow = tab + (size_t)gq[r * 16 + c][k] * FF;
            bf16x8 xa[4];
#pragma unroll
            for (int kk = 0; kk < 4; ++kk)
                xa[kk] = load_cvt8(xrow + kk * 32 + koff);
#pragma unroll
            for (int g = 0; g < 4; ++g)
#pragma unroll
                for (int kk = 0; kk < 4; ++kk)
                    acc[g][r] = __builtin_amdgcn_mfma_f32_16x16x32_bf16(
                        xa[kk], bWih[g][kk], acc[g][r], 0, 0, 0);
        }

        // h_{k-1} @ Whh^T (h==0 at k=0)
        if (k > 0) {
#pragma unroll
            for (int r = 0; r < 4; ++r) {
                bf16x8 ha[2];
#pragma unroll
                for (int kk = 0; kk < 2; ++kk)
                    ha[kk] = *(const bf16x8*)(h_lds + (r * 16 + c) * HS + kk * 32 + koff);
#pragma unroll
                for (int g = 0; g < 4; ++g)
#pragma unroll
                    for (int kk = 0; kk < 2; ++kk)
                        acc[g][r] = __builtin_amdgcn_mfma_f32_16x16x32_bf16(
                            ha[kk], bWhh[g][kk], acc[g][r], 0, 0, 0);
            }
        }

        // activations (lane-local: all 4 gates of a unit in the same lane/reg)
        const bool last = (k == KK - 1);
        __syncthreads();   // all waves done READING h_lds before overwrite
#pragma unroll
        for (int r = 0; r < 4; ++r)
#pragma unroll
            for (int reg = 0; reg < 4; ++reg) {
                float gi = fast_sig(acc[0][r][reg]);
                float gf = fast_sig(acc[1][r][reg]);
                float gg = fast_tanh(acc[2][r][reg]);
                float go = fast_sig(acc[3][r][reg]);
                float cn = gf * cst[r][reg] + gi * gg;
                cst[r][reg] = cn;
                float h = go * fast_tanh(cn);
                if (last) {
                    int node = node_base + r * 16 + q * 4 + reg;
                    if (node < NN) out[(size_t)node * 128 + w * 16 + c] = h;
                } else {
                    h_lds[(r * 16 + q * 4 + reg) * HS + w * 16 + c] = (__bf16)h;
                }
            }
        __syncthreads();   // h writes visible for next step's reads
    }

    // ---- backward direction: one step on x[:,9], zero state (f-gate moot) ----
    {
        const int gb[3] = {0, 2, 3};    // gates i, g, o
        bf16x8 bW[3][4];
        float  bb[3];
#pragma unroll
        for (int j = 0; j < 3; ++j) {
            int row = (gb[j] * 4 + w) * 16 + c;
#pragma unroll
            for (int kk = 0; kk < 4; ++kk)
                bW[j][kk] = *(const bf16x8*)(ws + WS_WIH_B + row * FF + kk * 32 + koff);
            int u = gb[j] * 64 + w * 16 + c;
            bb[j] = bih_b[u] + bhh_b[u];
        }
#pragma unroll
        for (int r = 0; r < 4; ++r) {
            f32x4 a0 = (f32x4){bb[0], bb[0], bb[0], bb[0]};
            f32x4 a1 = (f32x4){bb[1], bb[1], bb[1], bb[1]};
            f32x4 a2 = (f32x4){bb[2], bb[2], bb[2], bb[2]};
            const float* xrow = tab + (size_t)gq[r * 16 + c][KK - 1] * FF;
            bf16x8 xa[4];
#pragma unroll
            for (int kk = 0; kk < 4; ++kk)
                xa[kk] = load_cvt8(xrow + kk * 32 + koff);
#pragma unroll
            for (int kk = 0; kk < 4; ++kk) {
                a0 = __builtin_amdgcn_mfma_f32_16x16x32_bf16(xa[kk], bW[0][kk], a0, 0, 0, 0);
                a1 = __builtin_amdgcn_mfma_f32_16x16x32_bf16(xa[kk], bW[1][kk], a1, 0, 0, 0);
                a2 = __builtin_amdgcn_mfma_f32_16x16x32_bf16(xa[kk], bW[2][kk], a2, 0, 0, 0);
            }
#pragma unroll
            for (int reg = 0; reg < 4; ++reg) {
                float gi = fast_sig(a0[reg]);
                float gg = fast_tanh(a1[reg]);
                float go = fast_sig(a2[reg]);
                float hb = go * fast_tanh(gi * gg);
                int node = node_base + r * 16 + q * 4 + reg;
                if (node < NN) out[(size_t)node * 128 + 64 + w * 16 + c] = hb;
            }
        }
    }
}

extern "C" void kernel_launch(void* const* d_in, const int* in_sizes, int n_in,
                              void* d_out, int out_size, void* d_ws, size_t ws_size,
                              hipStream_t stream) {
    const int*   nidx  = (const int*)d_in[0];
    const float* tab   = (const float*)d_in[1];
    const float* Wih_f = (const float*)d_in[2];
    const float* Whh_f = (const float*)d_in[3];
    const float* bih_f = (const float*)d_in[4];
    const float* bhh_f = (const float*)d_in[5];
    const float* Wih_b = (const float*)d_in[6];
    // d_in[7] = Whh_b: mathematically unused (h0 = 0 for the backward stream)
    const float* bih_b = (const float*)d_in[8];
    const float* bhh_b = (const float*)d_in[9];
    __bf16* ws  = (__bf16*)d_ws;      // 160 KB scratch
    float*  out = (float*)d_out;      // output is f32

    hipLaunchKernelGGL(cvt_weights_kernel, dim3(32768 / 256), dim3(256), 0, stream,
                       Wih_f, Whh_f, Wih_b, ws);

    const int blocks = (NN + 63) / 64;   // 64 nodes per 256-thread block
    hipLaunchKernelGGL(lstm_agg_kernel, dim3(blocks), dim3(256), 0, stream,
                       nidx, tab, bih_f, bhh_f, bih_b, bhh_b, ws, out);
}